// Round 1
// baseline (233.125 us; speedup 1.0000x reference)
//
#include <hip/hip_runtime.h>

typedef unsigned short u16;
typedef __bf16 bf16x8 __attribute__((ext_vector_type(8)));
typedef float f32x4 __attribute__((ext_vector_type(4)));

// ---- fp32 -> bf16 (RNE) without header dependency ----
__device__ inline u16 f2bf(float f) {
  union { float f; unsigned u; } a; a.f = f;
  unsigned u = a.u;
  return (u16)((u + 0x7fffu + ((u >> 16) & 1u)) >> 16);
}

__device__ inline void store_c(float* p, float v) { *p = v; }
__device__ inline void store_c(u16* p, float v) { *p = f2bf(v); }

// ---- elementwise fp32 -> bf16 convert, 4 elems/thread ----
__global__ __launch_bounds__(256) void cvt_kernel(const float* __restrict__ in,
                                                  u16* __restrict__ out) {
  size_t i = ((size_t)blockIdx.x * 256 + threadIdx.x) * 4;
  float4 v = *(const float4*)(in + i);
  ushort4 o;
  o.x = f2bf(v.x); o.y = f2bf(v.y); o.z = f2bf(v.z); o.w = f2bf(v.w);
  *(ushort4*)(out + i) = o;
}

// ---- C = A @ B^T  (A:[M,K] rm w/ lda, B:[N,K] rm w/ ldb), bf16 in, CT out ----
// m97 structure: 128x128 tile, 4 waves (2x2 of 64x64), BK=32,
// global_load_lds width-16 staging, ds_read_b128 frags, 16x16x32 bf16 MFMA.
// SKIP_UPPER: causal QK^T — skip tiles with n0 > m0 (fully masked).
// KLIM: causal PV — K-loop limited to m0+128 (A rows are zero beyond diag).
template <typename CT, bool SKIP_UPPER, bool KLIM>
__global__ __launch_bounds__(256) void gemm_bt(
    const u16* __restrict__ A, const u16* __restrict__ B, CT* __restrict__ C,
    int K, int lda, int ldb, int ldc, long sA, long sB, long sC) {
  const int m0 = blockIdx.y * 128, n0 = blockIdx.x * 128;
  if (SKIP_UPPER && n0 > m0) return;  // tiles multiples of 128: n0>m0 <=> fully above diagonal
  A += (size_t)blockIdx.z * sA;
  B += (size_t)blockIdx.z * sB;
  C += (size_t)blockIdx.z * sC;
  const int Keff = KLIM ? (m0 + 128) : K;  // only used where m0+128 <= K

  __shared__ __align__(16) u16 As[128 * 32];
  __shared__ __align__(16) u16 Bs[128 * 32];

  const int tid = threadIdx.x;
  const int ln = tid & 63, wv = tid >> 6;
  const int wr = wv >> 1, wc = wv & 1;

  f32x4 acc[4][4] = {};

  for (int kt = 0; kt < Keff; kt += 32) {
    __syncthreads();  // prev iteration's LDS reads done before overwrite
#pragma unroll
    for (int i = 0; i < 2; ++i) {
      // chunk c: 16B each; LDS dest = wave-uniform base + lane*16 (HW requirement)
      const int c = (i * 4 + wv) * 64 + ln;
      const int row = c >> 2, col = (c & 3) * 8;
      const u16* ga = A + (size_t)(m0 + row) * lda + (kt + col);
      const u16* gb = B + (size_t)(n0 + row) * ldb + (kt + col);
      __builtin_amdgcn_global_load_lds(
          (const __attribute__((address_space(1))) void*)ga,
          (__attribute__((address_space(3))) void*)(&As[c * 8]), 16, 0, 0);
      __builtin_amdgcn_global_load_lds(
          (const __attribute__((address_space(1))) void*)gb,
          (__attribute__((address_space(3))) void*)(&Bs[c * 8]), 16, 0, 0);
    }
    __syncthreads();  // compiler drains vmcnt(0) before barrier

    bf16x8 af[4], bfv[4];
#pragma unroll
    for (int mi = 0; mi < 4; ++mi) {
      const int r = wr * 64 + mi * 16 + (ln & 15);
      af[mi] = *(const bf16x8*)&As[r * 32 + (ln >> 4) * 8];
    }
#pragma unroll
    for (int ni = 0; ni < 4; ++ni) {
      const int r = wc * 64 + ni * 16 + (ln & 15);
      bfv[ni] = *(const bf16x8*)&Bs[r * 32 + (ln >> 4) * 8];
    }
#pragma unroll
    for (int mi = 0; mi < 4; ++mi)
#pragma unroll
      for (int ni = 0; ni < 4; ++ni)
        acc[mi][ni] = __builtin_amdgcn_mfma_f32_16x16x32_bf16(af[mi], bfv[ni],
                                                              acc[mi][ni], 0, 0, 0);
  }

  // epilogue: D col = lane&15 (n), row = (lane>>4)*4 + reg (m) — m89-verified
#pragma unroll
  for (int mi = 0; mi < 4; ++mi) {
    const int rbase = m0 + wr * 64 + mi * 16 + ((ln >> 4) * 4);
#pragma unroll
    for (int ni = 0; ni < 4; ++ni) {
      const int col = n0 + wc * 64 + ni * 16 + (ln & 15);
#pragma unroll
      for (int r = 0; r < 4; ++r)
        store_c(&C[(size_t)(rbase + r) * ldc + col], acc[mi][ni][r]);
    }
  }
}

// ---- causal row softmax on fp32 scores, writes bf16 P in-place (row stride 4096 u16) ----
__global__ __launch_bounds__(256) void softmax_kernel(float* __restrict__ S, float scale) {
  const int q = blockIdx.x;
  float* row = S + ((size_t)blockIdx.y * 2048 + q) * 2048;
  const int t = threadIdx.x;
  // all reads happen before the first __syncthreads -> in-place rewrite is safe
  float4 v0 = *(const float4*)(row + t * 4);
  float4 v1 = *(const float4*)(row + 1024 + t * 4);
  float x[8] = {v0.x, v0.y, v0.z, v0.w, v1.x, v1.y, v1.z, v1.w};
  float m = -3.4e38f;
#pragma unroll
  for (int i = 0; i < 8; ++i) {
    const int j = (i < 4) ? (t * 4 + i) : (1024 + t * 4 + (i - 4));
    x[i] = (j <= q) ? x[i] * scale : -3.4e38f;  // mask BEFORE use (upper tiles hold garbage)
    m = fmaxf(m, x[i]);
  }
#pragma unroll
  for (int off = 32; off > 0; off >>= 1) m = fmaxf(m, __shfl_xor(m, off, 64));
  __shared__ float redm[4], reds[4];
  const int ln = t & 63, wv = t >> 6;
  if (ln == 0) redm[wv] = m;
  __syncthreads();
  m = fmaxf(fmaxf(redm[0], redm[1]), fmaxf(redm[2], redm[3]));

  float p[8];
  float s = 0.f;
#pragma unroll
  for (int i = 0; i < 8; ++i) {
    p[i] = __expf(x[i] - m);  // masked: exp(-3.4e38 - m) underflows to exact 0
    s += p[i];
  }
#pragma unroll
  for (int off = 32; off > 0; off >>= 1) s += __shfl_xor(s, off, 64);
  if (ln == 0) reds[wv] = s;
  __syncthreads();
  s = reds[0] + reds[1] + reds[2] + reds[3];
  const float r = 1.0f / s;

  u16* prow = (u16*)row;
  ushort4 o0, o1;
  o0.x = f2bf(p[0] * r); o0.y = f2bf(p[1] * r); o0.z = f2bf(p[2] * r); o0.w = f2bf(p[3] * r);
  o1.x = f2bf(p[4] * r); o1.y = f2bf(p[5] * r); o1.z = f2bf(p[6] * r); o1.w = f2bf(p[7] * r);
  *(ushort4*)(prow + t * 4) = o0;
  *(ushort4*)(prow + 1024 + t * 4) = o1;
}

extern "C" void kernel_launch(void* const* d_in, const int* in_sizes, int n_in,
                              void* d_out, int out_size, void* d_ws, size_t ws_size,
                              hipStream_t stream) {
  const float* x  = (const float*)d_in[0];
  const float* Wq = (const float*)d_in[1];
  const float* Wk = (const float*)d_in[2];
  const float* Wv = (const float*)d_in[3];
  float* out = (float*)d_out;

  // workspace layout (bytes): 134 MB total
  char* ws = (char*)d_ws;
  u16* xb   = (u16*)(ws);                        // 16 MB  x bf16 [8192][1024]
  u16* wqb  = (u16*)(ws + (16ul << 20));         //  2 MB
  u16* wkb  = (u16*)(ws + (18ul << 20));         //  2 MB
  u16* wvb  = (u16*)(ws + (20ul << 20));         //  2 MB
  u16* Qb   = (u16*)(ws + (22ul << 20));         // 16 MB  Q bf16 [4][2048][1024]
  u16* Kb   = (u16*)(ws + (38ul << 20));         // 16 MB  K bf16
  u16* VTb  = (u16*)(ws + (54ul << 20));         // 16 MB  V^T bf16 [4][1024][2048]
  float* Sb = (float*)(ws + (70ul << 20));       // 64 MB  scores fp32 [4][2048][2048] (P bf16 in-place)

  // fp32 -> bf16 converts
  cvt_kernel<<<8192, 256, 0, stream>>>(x, xb);
  cvt_kernel<<<1024, 256, 0, stream>>>(Wq, wqb);
  cvt_kernel<<<1024, 256, 0, stream>>>(Wk, wkb);
  cvt_kernel<<<1024, 256, 0, stream>>>(Wv, wvb);

  // Q = x @ Wq^T, K = x @ Wk^T   [8192,1024]
  gemm_bt<u16, false, false><<<dim3(8, 64, 1), 256, 0, stream>>>(
      xb, wqb, Qb, 1024, 1024, 1024, 1024, 0, 0, 0);
  gemm_bt<u16, false, false><<<dim3(8, 64, 1), 256, 0, stream>>>(
      xb, wkb, Kb, 1024, 1024, 1024, 1024, 0, 0, 0);

  // VT_b = Wv @ x_b^T   [1024,2048] per batch
  gemm_bt<u16, false, false><<<dim3(16, 8, 4), 256, 0, stream>>>(
      wvb, xb, VTb, 1024, 1024, 1024, 2048, 0, 2048l * 1024, 1024l * 2048);

  // S_b = Q_b @ K_b^T   [2048,2048] fp32, skip above-diagonal tiles
  gemm_bt<float, true, false><<<dim3(16, 16, 4), 256, 0, stream>>>(
      Qb, Kb, Sb, 1024, 1024, 1024, 2048, 2048l * 1024, 2048l * 1024, 2048l * 2048);

  // causal softmax (scale = 1/sqrt(1024)), P bf16 in-place
  softmax_kernel<<<dim3(2048, 4, 1), 256, 0, stream>>>(Sb, 0.03125f);

  // O_b = P_b @ VT_b^T  [2048,1024] fp32 -> d_out, K-loop limited to diagonal
  gemm_bt<float, false, true><<<dim3(8, 16, 4), 256, 0, stream>>>(
      (const u16*)Sb, VTb, out, 2048, 4096, 2048, 1024,
      2048l * 4096, 1024l * 2048, 2048l * 1024);
}